// Round 11
// baseline (491.014 us; speedup 1.0000x reference)
//
#include <hip/hip_runtime.h>
#include <hip/hip_bf16.h>
#include <cmath>

// Problem dims (fixed): B=512, T=128, F=256, H=128, 4H=512, M=B*T=65536
#define BB 512
#define TT 128
#define FF 256
#define HH 128
#define GG 512
#define MM 65536

typedef short bf16x8 __attribute__((ext_vector_type(8)));
typedef float f32x4 __attribute__((ext_vector_type(4)));

__device__ __forceinline__ float sigmf(float x) { return 1.0f / (1.0f + __expf(-x)); }
__device__ __forceinline__ float tanh_fast(float x) {
    return 1.0f - 2.0f / (__expf(2.0f * x) + 1.0f);
}
__device__ __forceinline__ short f2bf(float f) {
    __hip_bfloat16 h = __float2bfloat16(f);   // round-to-nearest-even
    return *reinterpret_cast<short*>(&h);
}
__device__ __forceinline__ float bf2f(short s) {
    unsigned int u = ((unsigned int)(unsigned short)s) << 16;
    return __uint_as_float(u);
}
__device__ __forceinline__ bf16x8 cvt8(const float* p) {
    bf16x8 r;
#pragma unroll
    for (int i = 0; i < 8; ++i) r[i] = f2bf(p[i]);
    return r;
}

// ---------------------------------------------------------------------------
// K1: per (b,f) lane over time.  Round-9: double-buffered load bursts in both
// passes (consume burst n while burst n+1 is in flight).
// ---------------------------------------------------------------------------
__global__ __launch_bounds__(256) void k1_preprocess(
    const float* __restrict__ X, const float* __restrict__ X_last,
    const float* __restrict__ W_x, const float* __restrict__ b_x,
    const float* __restrict__ W_attn,
    unsigned short* __restrict__ DX, float* __restrict__ SX, float* __restrict__ CM)
{
    const int b = blockIdx.x;
    const int f = threadIdx.x;
    __shared__ float wl[256];               // [wa_x(128) | wa_m(128)]
    wl[f] = W_attn[256 + f];
    __syncthreads();

    const float* xb  = X      + (size_t)b * TT * FF + f;
    const float* xlb = X_last + (size_t)b * TT * FF + f;

    // pass 1: mask bits, sum/count, c_mask  (16-wide dbuf bursts)
    unsigned long long mb0 = 0ull, mb1 = 0ull;
    float sum = 0.f, cnt = 0.f, cm = 0.f;
    float p0[16], p1[16];
#pragma unroll
    for (int i = 0; i < 16; ++i) p0[i] = xb[i * FF];
#define K1P1(ARR, TB)                                                        \
    {                                                                        \
        _Pragma("unroll")                                                    \
        for (int i = 0; i < 16; ++i) {                                       \
            int t = (TB) + i;                                                \
            bool m = (ARR[i] != -1.0f);                                      \
            if (m) {                                                         \
                sum += ARR[i]; cnt += 1.0f;                                  \
                if (t < 64) mb0 |= (1ull << t); else mb1 |= (1ull << (t - 64)); \
            }                                                                \
            cm += (m ? 1.0f : 0.0f) * wl[128 + t];                           \
        }                                                                    \
    }
    for (int tb = 0; tb < TT; tb += 32) {
#pragma unroll
        for (int i = 0; i < 16; ++i) p1[i] = xb[(tb + 16 + i) * FF];
        K1P1(p0, tb)
#pragma unroll
        for (int i = 0; i < 16; ++i) {
            int tt = tb + 32 + i; tt = (tt < TT) ? tt : (TT - 1);
            p0[i] = xb[tt * FF];
        }
        K1P1(p1, tb + 16)
    }
#undef K1P1
    const float mean = (cnt > 0.f) ? (sum / cnt) : 0.f;
    CM[(size_t)b * FF + f] = cm;

    const float wxd = W_x[(size_t)f * FF + f];
    const float bx  = b_x[f];
    unsigned short* dxb = DX + (size_t)b * TT * FF + f;
    float* sxb = SX + (size_t)b * TT * FF + f;

    // pass 2: deltaX, X_new, running cumsum  (8+8 dbuf bursts)
    float d = 0.f, s = 0.f;
    bool mprev = false;
    float xv0[8], xl0[8], xv1[8], xl1[8];
#pragma unroll
    for (int i = 0; i < 8; ++i) { xv0[i] = xb[i * FF]; xl0[i] = xlb[i * FF]; }
#define K1P2(XA, LA, TB)                                                     \
    {                                                                        \
        _Pragma("unroll")                                                    \
        for (int i = 0; i < 8; ++i) {                                        \
            int t = (TB) + i;                                                \
            bool m = (t < 64) ? ((mb0 >> t) & 1ull) : ((mb1 >> (t - 64)) & 1ull); \
            if (t > 0) d = mprev ? 1.0f : (d + 1.0f);                        \
            mprev = m;                                                       \
            dxb[t * FF] = (unsigned short)f2bf(d);                           \
            float x0  = m ? XA[i] : 0.f;                                     \
            float dxv = __expf(-fmaxf(fmaf(d, wxd, bx), 0.f));               \
            float xnew = m ? x0 : (dxv * LA[i] + (1.0f - dxv) * mean);       \
            s += xnew * wl[t];                                               \
            sxb[t * FF] = s;                                                 \
        }                                                                    \
    }
    for (int tb = 0; tb < TT; tb += 16) {
#pragma unroll
        for (int i = 0; i < 8; ++i) {
            int tt = tb + 8 + i;
            xv1[i] = xb[tt * FF]; xl1[i] = xlb[tt * FF];
        }
        K1P2(xv0, xl0, tb)
#pragma unroll
        for (int i = 0; i < 8; ++i) {
            int tt = tb + 16 + i; tt = (tt < TT) ? tt : (TT - 1);
            xv0[i] = xb[tt * FF]; xl0[i] = xlb[tt * FF];
        }
        K1P2(xv1, xl1, tb + 8)
    }
#undef K1P2
}

// ---------------------------------------------------------------------------
// K2: bf16 MFMA GEMM (Dh).  (unchanged from verified Round-7 version)
// ---------------------------------------------------------------------------
__global__ __launch_bounds__(256) void k2_gemm_dh_mfma(
    const unsigned short* __restrict__ A,  // DX bf16 (M,256)
    const float* __restrict__ W,           // W_h (128,256) f32
    const float* __restrict__ bias1,       // b_h
    float* __restrict__ C)                 // Dh (M,128) f32
{
    __shared__ short As[128 * 64];
    __shared__ short Bh[128 * 64];
    __shared__ short Bl[128 * 64];

    const int tid  = threadIdx.x;
    const int lane = tid & 63;
    const int wave = tid >> 6;
    const int wm = wave >> 1, wn = wave & 1;
    const int r0 = blockIdx.x * 128;

    f32x4 acc[4][4] = {};

    for (int kc = 0; kc < 256; kc += 64) {
#pragma unroll
        for (int i = 0; i < 4; ++i) {
            int slot = i * 256 + tid;
            int row = slot >> 3, kg = slot & 7;
            int byte = (row * 128 + kg * 16) ^ ((row & 7) << 4);
            *(bf16x8*)((char*)As + byte) =
                *(const bf16x8*)&A[(size_t)(r0 + row) * 256 + kc + kg * 8];
            float tmp[8];
            *(float4*)&tmp[0] = *(const float4*)&W[(size_t)row * 256 + kc + kg * 8];
            *(float4*)&tmp[4] = *(const float4*)&W[(size_t)row * 256 + kc + kg * 8 + 4];
            bf16x8 hi, lo;
#pragma unroll
            for (int j = 0; j < 8; ++j) {
                hi[j] = f2bf(tmp[j]);
                lo[j] = f2bf(tmp[j] - bf2f(hi[j]));
            }
            *(bf16x8*)((char*)Bh + byte) = hi;
            *(bf16x8*)((char*)Bl + byte) = lo;
        }
        __syncthreads();

#pragma unroll
        for (int ks = 0; ks < 2; ++ks) {
            bf16x8 af[4], bh[4], bl[4];
#pragma unroll
            for (int mf = 0; mf < 4; ++mf) {
                int row = wm * 64 + mf * 16 + (lane & 15);
                int byte = (row * 128 + ks * 64 + (lane >> 4) * 16) ^ ((row & 7) << 4);
                af[mf] = *(const bf16x8*)((const char*)As + byte);
            }
#pragma unroll
            for (int nf = 0; nf < 4; ++nf) {
                int row = wn * 64 + nf * 16 + (lane & 15);
                int byte = (row * 128 + ks * 64 + (lane >> 4) * 16) ^ ((row & 7) << 4);
                bh[nf] = *(const bf16x8*)((const char*)Bh + byte);
                bl[nf] = *(const bf16x8*)((const char*)Bl + byte);
            }
#pragma unroll
            for (int mf = 0; mf < 4; ++mf)
#pragma unroll
                for (int nf = 0; nf < 4; ++nf) {
                    acc[mf][nf] = __builtin_amdgcn_mfma_f32_16x16x32_bf16(
                        af[mf], bh[nf], acc[mf][nf], 0, 0, 0);
                    acc[mf][nf] = __builtin_amdgcn_mfma_f32_16x16x32_bf16(
                        af[mf], bl[nf], acc[mf][nf], 0, 0, 0);
                }
        }
        __syncthreads();
    }

    float b1[4];
#pragma unroll
    for (int nf = 0; nf < 4; ++nf) b1[nf] = bias1[wn * 64 + nf * 16 + (lane & 15)];
#pragma unroll
    for (int mf = 0; mf < 4; ++mf)
#pragma unroll
        for (int nf = 0; nf < 4; ++nf) {
            int col = wn * 64 + nf * 16 + (lane & 15);
#pragma unroll
            for (int reg = 0; reg < 4; ++reg) {
                int row = r0 + wm * 64 + mf * 16 + (lane >> 4) * 4 + reg;
                C[(size_t)row * HH + col] = __expf(-fmaxf(acc[mf][nf][reg] + b1[nf], 0.f));
            }
        }
}

// ---------------------------------------------------------------------------
// K3: alpha = softmax_f(Sx + c_mask); X_tilde = alpha * X0.  (unchanged)
// ---------------------------------------------------------------------------
__global__ __launch_bounds__(256) void k3_softmax(
    const float* __restrict__ SX, const float* __restrict__ CM,
    const float* __restrict__ X, float* __restrict__ Xt)
{
    const int tid  = threadIdx.x;
    const int lane = tid & 63;
    const int w    = tid >> 6;
    const int r    = blockIdx.x * 4 + w;
    const int b    = r >> 7;

    const float4 sx = *(const float4*)&SX[(size_t)r * FF + lane * 4];
    const float4 cm = *(const float4*)&CM[(size_t)b * FF + lane * 4];
    float s0 = sx.x + cm.x, s1 = sx.y + cm.y, s2 = sx.z + cm.z, s3 = sx.w + cm.w;

    float mx = fmaxf(fmaxf(s0, s1), fmaxf(s2, s3));
#pragma unroll
    for (int o = 32; o > 0; o >>= 1) mx = fmaxf(mx, __shfl_xor(mx, o));
    float e0 = __expf(s0 - mx), e1 = __expf(s1 - mx);
    float e2 = __expf(s2 - mx), e3 = __expf(s3 - mx);
    float sm = e0 + e1 + e2 + e3;
#pragma unroll
    for (int o = 32; o > 0; o >>= 1) sm += __shfl_xor(sm, o);
    float inv = 1.0f / sm;

    const float4 xv = *(const float4*)&X[(size_t)r * FF + lane * 4];
    float4 o4;
    o4.x = ((xv.x != -1.0f) ? xv.x : 0.f) * e0 * inv;
    o4.y = ((xv.y != -1.0f) ? xv.y : 0.f) * e1 * inv;
    o4.z = ((xv.z != -1.0f) ? xv.z : 0.f) * e2 * inv;
    o4.w = ((xv.w != -1.0f) ? xv.w : 0.f) * e3 * inv;
    *(float4*)&Xt[(size_t)r * FF + lane * 4] = o4;
}

// ---------------------------------------------------------------------------
// K4: bf16 MFMA GEMM.  G = Xt @ W_ih^T + b_ih + b_hh.  (unchanged)
// ---------------------------------------------------------------------------
__global__ __launch_bounds__(256) void k4_gemm_bf16(
    const float* __restrict__ A, const float* __restrict__ W,
    const float* __restrict__ bias1, const float* __restrict__ bias2,
    float* __restrict__ C)
{
    __shared__ short As[128 * 64];
    __shared__ short Bs[128 * 64];

    const int tid  = threadIdx.x;
    const int lane = tid & 63;
    const int wave = tid >> 6;
    const int wm = wave >> 1, wn = wave & 1;
    const int r0 = blockIdx.x * 128;
    const int c0 = blockIdx.y * 128;

    f32x4 acc[4][4] = {};

    for (int kc = 0; kc < 256; kc += 64) {
#pragma unroll
        for (int i = 0; i < 4; ++i) {
            int slot = i * 256 + tid;
            int row = slot >> 3, kg = slot & 7;
            int byte = (row * 128 + kg * 16) ^ ((row & 7) << 4);
            float tmp[8];
            *(float4*)&tmp[0] = *(const float4*)&A[(size_t)(r0 + row) * 256 + kc + kg * 8];
            *(float4*)&tmp[4] = *(const float4*)&A[(size_t)(r0 + row) * 256 + kc + kg * 8 + 4];
            *(bf16x8*)((char*)As + byte) = cvt8(tmp);
            *(float4*)&tmp[0] = *(const float4*)&W[(size_t)(c0 + row) * 256 + kc + kg * 8];
            *(float4*)&tmp[4] = *(const float4*)&W[(size_t)(c0 + row) * 256 + kc + kg * 8 + 4];
            *(bf16x8*)((char*)Bs + byte) = cvt8(tmp);
        }
        __syncthreads();

#pragma unroll
        for (int ks = 0; ks < 2; ++ks) {
            bf16x8 af[4], bw[4];
#pragma unroll
            for (int mf = 0; mf < 4; ++mf) {
                int row = wm * 64 + mf * 16 + (lane & 15);
                int byte = (row * 128 + ks * 64 + (lane >> 4) * 16) ^ ((row & 7) << 4);
                af[mf] = *(const bf16x8*)((const char*)As + byte);
            }
#pragma unroll
            for (int nf = 0; nf < 4; ++nf) {
                int row = wn * 64 + nf * 16 + (lane & 15);
                int byte = (row * 128 + ks * 64 + (lane >> 4) * 16) ^ ((row & 7) << 4);
                bw[nf] = *(const bf16x8*)((const char*)Bs + byte);
            }
#pragma unroll
            for (int mf = 0; mf < 4; ++mf)
#pragma unroll
                for (int nf = 0; nf < 4; ++nf)
                    acc[mf][nf] = __builtin_amdgcn_mfma_f32_16x16x32_bf16(
                        af[mf], bw[nf], acc[mf][nf], 0, 0, 0);
        }
        __syncthreads();
    }

    float bsum[4];
#pragma unroll
    for (int nf = 0; nf < 4; ++nf) {
        int col = c0 + wn * 64 + nf * 16 + (lane & 15);
        bsum[nf] = bias1[col] + bias2[col];
    }
#pragma unroll
    for (int mf = 0; mf < 4; ++mf)
#pragma unroll
        for (int nf = 0; nf < 4; ++nf) {
            int col = c0 + wn * 64 + nf * 16 + (lane & 15);
#pragma unroll
            for (int reg = 0; reg < 4; ++reg) {
                int row = r0 + wm * 64 + mf * 16 + (lane >> 4) * 4 + reg;
                C[(size_t)row * GG + col] = acc[mf][nf][reg] + bsum[nf];
            }
        }
}

// ---------------------------------------------------------------------------
// K5: sequential recurrence via MFMA.  Round-9 changes:
//  * RAW barrier (lgkmcnt(0) + s_barrier) instead of __syncthreads():
//    __syncthreads drains vmcnt(0) at every step, stalling ~700+ cycles on
//    the G/Dh prefetch loads.  The raw pattern (m194-m201-verified) keeps
//    global loads in flight across barriers; LDS visibility is preserved
//    because each wave drains its OWN ds_writes (lgkmcnt) before barrier.
//  * Pair-unrolled t-loop with 2-step-ahead prefetch into named registers
//    (load-to-use distance = 2 full steps >> HBM latency).
//  * Split hi/lo MFMA accumulators (dep chains 8 -> 4 deep).
// Dh alias: reads (t+3/t+4) precede Xenc writes (t,t+1) in program order at
// strictly higher addresses -> safe.
// ---------------------------------------------------------------------------
__device__ __forceinline__ void k5_step(
    int t, int rb, float gq0, float gq1, float gq2, float gq3, float dnx,
    float& cst, const bf16x8 (&wf)[4][4], short (&hbuf)[2][2][2][160],
    int lane, int r, int w, int l, bool st, float* __restrict__ xb)
{
    asm volatile("s_waitcnt lgkmcnt(0)" ::: "memory");
    __builtin_amdgcn_s_barrier();

    f32x4 acch[4] = {}, accl[4] = {};
#pragma unroll
    for (int ks = 0; ks < 4; ++ks) {
        const bf16x8 afh = *(const bf16x8*)&hbuf[rb][0][lane & 1][ks * 32 + (lane >> 4) * 8];
        const bf16x8 afl = *(const bf16x8*)&hbuf[rb][1][lane & 1][ks * 32 + (lane >> 4) * 8];
#pragma unroll
        for (int q = 0; q < 4; ++q) {
            acch[q] = __builtin_amdgcn_mfma_f32_16x16x32_bf16(afh, wf[q][ks], acch[q], 0, 0, 0);
            accl[q] = __builtin_amdgcn_mfma_f32_16x16x32_bf16(afl, wf[q][ks], accl[q], 0, 0, 0);
        }
    }

    float gi = (r ? (acch[0][1] + accl[0][1]) : (acch[0][0] + accl[0][0])) + gq0;
    float gf = (r ? (acch[1][1] + accl[1][1]) : (acch[1][0] + accl[1][0])) + gq1;
    float gg = (r ? (acch[2][1] + accl[2][1]) : (acch[2][0] + accl[2][0])) + gq2;
    float go = (r ? (acch[3][1] + accl[3][1]) : (acch[3][0] + accl[3][0])) + gq3;
    float c = sigmf(gf) * cst + sigmf(gi) * tanh_fast(gg);
    cst = c;
    float h = sigmf(go) * tanh_fast(c);
    float hp = dnx * h;
    short hhi = f2bf(hp);
    short hlo = f2bf(hp - bf2f(hhi));
    if (st) {
        xb[(size_t)t * HH] = h;
        hbuf[rb ^ 1][0][r][w * 16 + l] = hhi;
        hbuf[rb ^ 1][1][r][w * 16 + l] = hlo;
    }
}

__global__ __launch_bounds__(512) void k5_recurrence_mfma(
    const float* __restrict__ Dh, const float* __restrict__ G,
    const float* __restrict__ W_hh, float* __restrict__ Xenc)
{
    __shared__ short hbuf[2][2][2][160];   // [buf][hi/lo][row][k padded]
    const int tid  = threadIdx.x;
    const int lane = tid & 63;
    const int w    = tid >> 6;             // wave 0..7
    const int b0   = blockIdx.x * 2;
    const int l    = lane & 15;
    const int r    = (lane >> 4) & 1;      // batch-row for this lane group
    const bool st  = (lane < 32);          // lanes 32-63 compute replicas

    bf16x8 wf[4][4];
#pragma unroll
    for (int q = 0; q < 4; ++q)
#pragma unroll
        for (int ks = 0; ks < 4; ++ks) {
            int gate = q * 128 + w * 16 + l;
            const float* src = &W_hh[(size_t)gate * HH + ks * 32 + (lane >> 4) * 8];
            float tmp[8];
            *(float4*)&tmp[0] = *(const float4*)&src[0];
            *(float4*)&tmp[4] = *(const float4*)&src[4];
            wf[q][ks] = cvt8(tmp);
        }

    for (int i = tid; i < 2 * 2 * 2 * 160; i += 512) ((short*)hbuf)[i] = 0;

    const float* gb = G    + (size_t)(b0 + r) * TT * GG + w * 16 + l;
    const float* db = Dh   + (size_t)(b0 + r) * TT * HH + w * 16 + l;
    float*       xb = Xenc + (size_t)(b0 + r) * TT * HH + w * 16 + l;

    float cst = 0.f;
    // preload G rows t=0,1 and Dh for use at t=0,1 (Dh[1], Dh[2])
    float gA0 = gb[0], gA1 = gb[128], gA2 = gb[256], gA3 = gb[384];
    const float* g1p = gb + GG;
    float gB0 = g1p[0], gB1 = g1p[128], gB2 = g1p[256], gB3 = g1p[384];
    float dA = db[(size_t)1 * HH];
    float dB = db[(size_t)2 * HH];

    for (int tp = 0; tp < TT; tp += 2) {
        // issue prefetch for steps tp+2 / tp+3 (clamped; consumed next pair)
        const int t2 = (tp + 2 < TT) ? tp + 2 : TT - 1;
        const int t3 = (tp + 3 < TT) ? tp + 3 : TT - 1;
        const int d2 = (tp + 3 < TT) ? tp + 3 : TT - 1;   // Dh[t2+1]
        const int d3 = (tp + 4 < TT) ? tp + 4 : TT - 1;   // Dh[t3+1]
        const float* g2p = gb + (size_t)t2 * GG;
        const float* g3p = gb + (size_t)t3 * GG;
        float n20 = g2p[0], n21 = g2p[128], n22 = g2p[256], n23 = g2p[384];
        float n30 = g3p[0], n31 = g3p[128], n32 = g3p[256], n33 = g3p[384];
        float nd2 = db[(size_t)d2 * HH];
        float nd3 = db[(size_t)d3 * HH];

        k5_step(tp,     0, gA0, gA1, gA2, gA3, dA, cst, wf, hbuf, lane, r, w, l, st, xb);
        k5_step(tp + 1, 1, gB0, gB1, gB2, gB3, dB, cst, wf, hbuf, lane, r, w, l, st, xb);

        gA0 = n20; gA1 = n21; gA2 = n22; gA3 = n23;
        gB0 = n30; gB1 = n31; gB2 = n32; gB3 = n33;
        dA = nd2; dB = nd3;
    }
}

// ---------------------------------------------------------------------------
extern "C" void kernel_launch(void* const* d_in, const int* in_sizes, int n_in,
                              void* d_out, int out_size, void* d_ws, size_t ws_size,
                              hipStream_t stream)
{
    const float* X      = (const float*)d_in[0];
    const float* X_last = (const float*)d_in[1];
    const float* W_x    = (const float*)d_in[2];
    const float* b_x    = (const float*)d_in[3];
    const float* W_h    = (const float*)d_in[4];
    const float* b_h    = (const float*)d_in[5];
    const float* W_ih   = (const float*)d_in[6];
    const float* b_ih   = (const float*)d_in[7];
    const float* W_hh   = (const float*)d_in[8];
    const float* b_hh   = (const float*)d_in[9];
    const float* W_attn = (const float*)d_in[10];

    float* ws = (float*)d_ws;
    // layout:
    //   DXbf (ushort): bytes [0, 33,554,432)            dead after K2
    //   SX (f32):      float idx [8,388,608, 25,165,824) dead after K3
    //   G  (f32):      float idx [0, 33,554,432)         written by K4
    //   CM (f32):      float idx [33,554,432, ...)       beyond G
    unsigned short* DXbf = (unsigned short*)ws;
    float* SX = ws + (size_t)8388608;
    float* Gb = ws;
    float* CM = ws + (size_t)33554432;

    float* Xt   = (float*)d_out;                       // (B,T,F)
    float* Xenc = (float*)d_out + (size_t)16777216;    // (B,T,H)
    float* DH   = Xenc;                                // aliased (see K5)

    k1_preprocess<<<BB, 256, 0, stream>>>(X, X_last, W_x, b_x, W_attn, DXbf, SX, CM);
    k2_gemm_dh_mfma<<<MM / 128, 256, 0, stream>>>(DXbf, W_h, b_h, DH);
    k3_softmax<<<MM / 4, 256, 0, stream>>>(SX, CM, X, Xt);
    k4_gemm_bf16<<<dim3(MM / 128, 4), 256, 0, stream>>>(Xt, W_ih, b_ih, b_hh, Gb);
    k5_recurrence_mfma<<<BB / 2, 512, 0, stream>>>(DH, Gb, W_hh, Xenc);
}